// Round 12
// baseline (50.137 us; speedup 1.0000x reference)
//
#include <hip/hip_runtime.h>
#include <hip/hip_fp16.h>

// Problem constants (reference: B,N,D,H,C = 4,512,128,128,3)
#define B_ 4
#define N_ 512
#define D_ 128
#define H_ 128
#define C_ 3

#define NEG_LOG2E   (-1.4426950408889634f)
#define NEG_HALF_LN2 (-0.34657359027997264f)   // -0.5 * ln(2)

#define PH   4     // h phases in pair kernel
#define PHH  32    // h per phase
#define SROW 40    // f16 LDS row stride: 80 B = 20 banks; 16-row reads <=2-way, 4-row disjoint

typedef _Float16 half8  __attribute__((ext_vector_type(8)));
typedef _Float16 half4v __attribute__((ext_vector_type(4)));

__device__ __forceinline__ float exp2_fast(float x) {
    return __builtin_amdgcn_exp2f(x);   // raw v_exp_f32 (2^x)
}

// Projections stored PRE-SCALED by -log2e, in f16:
//   At[row][h] = f16(-log2e * (dot(h[row], W1[h][0:128]) + b1[h]))
//   Bt[row][h] = f16(-log2e *  dot(h[row], W1[h][128:256]))
__global__ __launch_bounds__(256) void proj_gemm(
    const float* __restrict__ hd, const float* __restrict__ W1,
    const float* __restrict__ b1, _Float16* __restrict__ At, _Float16* __restrict__ Bt)
{
    __shared__ float hsT[64][36];   // [k][m]
    __shared__ float wt [64][68];   // [k][o]
    const int m0      = blockIdx.x * 32;
    const int by      = blockIdx.y;        // 0..3
    const int halfSel = by >> 1;           // 0 -> At, 1 -> Bt
    const int wrow0   = (by & 1) * 64;     // W1 row base (== output h-col base)

    const int t  = threadIdx.x;
    const int r  = t >> 4, c4 = t & 15;
    const int tx = t & 15, ty = t >> 4;

    float acc[2][4] = {};

    for (int kc = 0; kc < 2; ++kc) {
        if (kc) __syncthreads();
        #pragma unroll
        for (int i = 0; i < 2; ++i) {
            const int m = r + 16 * i;
            float4 v = *(const float4*)&hd[(m0 + m) * D_ + kc * 64 + 4 * c4];
            hsT[4 * c4 + 0][m] = v.x; hsT[4 * c4 + 1][m] = v.y;
            hsT[4 * c4 + 2][m] = v.z; hsT[4 * c4 + 3][m] = v.w;
        }
        #pragma unroll
        for (int i = 0; i < 4; ++i) {
            const int o = r + 16 * i;
            float4 v = *(const float4*)&W1[(wrow0 + o) * (2 * D_) + halfSel * D_ + kc * 64 + 4 * c4];
            wt[4 * c4 + 0][o] = v.x; wt[4 * c4 + 1][o] = v.y;
            wt[4 * c4 + 2][o] = v.z; wt[4 * c4 + 3][o] = v.w;
        }
        __syncthreads();
        #pragma unroll 8
        for (int k = 0; k < 64; ++k) {
            float2 a  = *(const float2*)&hsT[k][2 * ty];
            float4 bv = *(const float4*)&wt [k][4 * tx];
            acc[0][0] = fmaf(a.x, bv.x, acc[0][0]); acc[0][1] = fmaf(a.x, bv.y, acc[0][1]);
            acc[0][2] = fmaf(a.x, bv.z, acc[0][2]); acc[0][3] = fmaf(a.x, bv.w, acc[0][3]);
            acc[1][0] = fmaf(a.y, bv.x, acc[1][0]); acc[1][1] = fmaf(a.y, bv.y, acc[1][1]);
            acc[1][2] = fmaf(a.y, bv.z, acc[1][2]); acc[1][3] = fmaf(a.y, bv.w, acc[1][3]);
        }
    }

    _Float16* dst = halfSel ? Bt : At;
    const int ocol = wrow0 + 4 * tx;
    float4 bias = make_float4(0.f, 0.f, 0.f, 0.f);
    if (!halfSel) bias = *(const float4*)&b1[ocol];
    #pragma unroll
    for (int i = 0; i < 2; ++i) {
        half4v o;
        o[0] = (_Float16)((acc[i][0] + bias.x) * NEG_LOG2E);
        o[1] = (_Float16)((acc[i][1] + bias.y) * NEG_LOG2E);
        o[2] = (_Float16)((acc[i][2] + bias.z) * NEG_LOG2E);
        o[3] = (_Float16)((acc[i][3] + bias.w) * NEG_LOG2E);
        *(half4v*)&dst[(m0 + 2 * ty + i) * H_ + ocol] = o;
    }
}

// One block per (batch, I16xJ32 tile pair). Tile-pairs enumerated with
// it < 2*jt+2 (I-tile starts before J-tile ends) -> 272 tiles -> 1088 blocks.
// Thread (ti,tj) owns pairs (I0+ti, J0+tj) and (I0+ti, J0+tj+16): the i-row
// data is shared across both -> 12 B LDS per pair-h (vs 16 for 1-pair).
// Duplicated pairs across straddling tiles are computed BIT-IDENTICALLY
// (symmetric num = mul,mul,add with contract off) so racing writes are benign.
// Exp-factorized f16 math: e^(yi+yj) = Ei*Ej, exps once per row at staging.
__global__ __launch_bounds__(256, 3) void pair_kernel(
    const _Float16* __restrict__ At, const _Float16* __restrict__ Bt,
    const float* __restrict__ W2, const float* __restrict__ b2,
    float* __restrict__ out)
{
    // row space: 0-15 A/I-tile, 16-31 B/I-tile, 32-63 A/J-tile, 64-95 B/J-tile
    __shared__ __align__(16) _Float16 yt[96 * SROW];   // 7680 B
    __shared__ __align__(16) _Float16 et[96 * SROW];   // 7680 B

    const int b = blockIdx.y;
    int tp = blockIdx.x;
    int jt = 0;
    while (tp >= 2 * jt + 2) { tp -= 2 * jt + 2; ++jt; }   // uniform decode, <=16 iters
    const int it = tp;
    const int I0 = it * 16, J0 = jt * 32;

    const int tid = threadIdx.x;
    const int ti = tid >> 4, tj = tid & 15;

    float acc[2][3] = {};

    for (int ph = 0; ph < PH; ++ph) {
        if (ph) __syncthreads();   // reads of previous phase done before overwrite
        // stage 96 rows x 4 chunks (8 f16 each): global load + exp + 2 LDS writes
        for (int u = tid; u < 384; u += 256) {
            const int row = u >> 2, c = u & 3;
            const _Float16* base;
            int gr;
            if (row < 32)      { base = (row < 16) ? At : Bt; gr = I0 + (row & 15); }
            else if (row < 64) { base = At; gr = J0 + (row - 32); }
            else               { base = Bt; gr = J0 + (row - 64); }
            half8 yv = *(const half8*)&base[(size_t)(b * N_ + gr) * H_ + ph * PHH + c * 8];
            half8 ev;
            #pragma unroll
            for (int e = 0; e < 8; ++e)
                ev[e] = (_Float16)exp2_fast((float)yv[e]);
            *(half8*)&yt[row * SROW + c * 8] = yv;
            *(half8*)&et[row * SROW + c * 8] = ev;
        }
        __syncthreads();

        #pragma unroll 2
        for (int c = 0; c < 4; ++c) {
            const int oAi  = ( 0 + ti) * SROW + c * 8;
            const int oBi  = (16 + ti) * SROW + c * 8;
            const int oAj0 = (32 + tj) * SROW + c * 8;
            const int oAj1 = (48 + tj) * SROW + c * 8;
            const int oBj0 = (64 + tj) * SROW + c * 8;
            const int oBj1 = (80 + tj) * SROW + c * 8;
            half8 yAi  = *(const half8*)&yt[oAi],  eAi  = *(const half8*)&et[oAi];
            half8 yBi  = *(const half8*)&yt[oBi],  eBi  = *(const half8*)&et[oBi];
            half8 yAj0 = *(const half8*)&yt[oAj0], eAj0 = *(const half8*)&et[oAj0];
            half8 yAj1 = *(const half8*)&yt[oAj1], eAj1 = *(const half8*)&et[oAj1];
            half8 yBj0 = *(const half8*)&yt[oBj0], eBj0 = *(const half8*)&et[oBj0];
            half8 yBj1 = *(const half8*)&yt[oBj1], eBj1 = *(const half8*)&et[oBj1];

            const int hb = ph * PHH + c * 8;
            float4 w0a = *(const float4*)&W2[hb],          w0b = *(const float4*)&W2[hb + 4];
            float4 w1a = *(const float4*)&W2[H_ + hb],     w1b = *(const float4*)&W2[H_ + hb + 4];
            float4 w2a = *(const float4*)&W2[2 * H_ + hb], w2b = *(const float4*)&W2[2 * H_ + hb + 4];
            const float w0[8] = {w0a.x, w0a.y, w0a.z, w0a.w, w0b.x, w0b.y, w0b.z, w0b.w};
            const float w1[8] = {w1a.x, w1a.y, w1a.z, w1a.w, w1b.x, w1b.y, w1b.z, w1b.w};
            const float w2[8] = {w2a.x, w2a.y, w2a.z, w2a.w, w2b.x, w2b.y, w2b.z, w2b.w};

            // Symmetric under (1<->2) swap: e-products use fixed (A,B) operand
            // order; num = (y1*d2) + (y2*d1) with contraction off so duplicate
            // blocks produce bit-identical results.
            #define SILU2(p, yAj, yBj, eAj, eBj)                                  \
            {                                                                     \
                half8 y1 = yAi + (yBj);                                           \
                half8 y2 = (yAj) + yBi;                                           \
                half8 e1 = eAi * (eBj);                                           \
                half8 e2 = (eAj) * eBi;                                           \
                half8 d1 = e1 + (_Float16)1.0f;                                   \
                half8 d2 = e2 + (_Float16)1.0f;                                   \
                half8 pp = d1 * d2;                                               \
                half8 t1 = y1 * d2;                                               \
                half8 t2 = y2 * d1;                                               \
                half8 num;                                                        \
                { _Pragma("clang fp contract(off)") num = t1 + t2; }              \
                _Pragma("unroll")                                                 \
                for (int e = 0; e < 8; ++e) {                                     \
                    const float s = (float)num[e]                                 \
                                  * __builtin_amdgcn_rcpf((float)pp[e]);          \
                    acc[p][0] = fmaf(s, w0[e], acc[p][0]);                        \
                    acc[p][1] = fmaf(s, w1[e], acc[p][1]);                        \
                    acc[p][2] = fmaf(s, w2[e], acc[p][2]);                        \
                }                                                                 \
            }
            SILU2(0, yAj0, yBj0, eAj0, eBj0)
            SILU2(1, yAj1, yBj1, eAj1, eBj1)
            #undef SILU2
        }
    }

    const float b20 = b2[0], b21 = b2[1], b22 = b2[2];
    #pragma unroll
    for (int p = 0; p < 2; ++p) {
        const int i = I0 + ti;
        const int j = J0 + tj + p * 16;
        const float o0 = fmaf(NEG_HALF_LN2, acc[p][0], b20);
        const float o1 = fmaf(NEG_HALF_LN2, acc[p][1], b21);
        const float o2 = fmaf(NEG_HALF_LN2, acc[p][2], b22);
        float* p1 = out + ((size_t)(b * N_ + i) * N_ + j) * C_;
        float* p2 = out + ((size_t)(b * N_ + j) * N_ + i) * C_;
        p1[0] = o0; p1[1] = o1; p1[2] = o2;
        p2[0] = o0; p2[1] = o1; p2[2] = o2;   // duplicates are bit-identical -> benign
    }
}

extern "C" void kernel_launch(void* const* d_in, const int* in_sizes, int n_in,
                              void* d_out, int out_size, void* d_ws, size_t ws_size,
                              hipStream_t stream) {
    const float* hd = (const float*)d_in[0];
    const float* W1 = (const float*)d_in[1];
    const float* b1 = (const float*)d_in[2];
    const float* W2 = (const float*)d_in[3];
    const float* b2 = (const float*)d_in[4];
    float* out = (float*)d_out;

    _Float16* At = (_Float16*)d_ws;          // [B*N][H] f16 = 512 KiB (scaled by -log2e)
    _Float16* Bt = At + B_ * N_ * H_;        // [B*N][H] f16 = 512 KiB

    proj_gemm<<<dim3((B_ * N_) / 32, 4), dim3(256), 0, stream>>>(hd, W1, b1, At, Bt);

    // I16xJ32 tile pairs with it < 2*jt+2: sum_{jt=0}^{15} (2jt+2) = 272
    pair_kernel<<<dim3(272, B_), dim3(256), 0, stream>>>(At, Bt, W2, b2, out);
}